// Round 4
// baseline (2895.711 us; speedup 1.0000x reference)
//
#include <hip/hip_runtime.h>
#include <hip/hip_bf16.h>

#define MC 4096
#define DD 128
#define NHH 4
#define DH 32
#define FFD 256
#define NS 3
#define NSPLIT 4
#define PLEN 1024

__device__ __forceinline__ int getM(int s, const int* M0, const int* M1, const int* M2) {
    return (s == 0) ? *M0 : (s == 1) ? *M1 : *M2;
}

// ---------------- parent maps from inv arrays (nested grids) ----------------
__global__ void k_parent(const int* __restrict__ inv0, const int* __restrict__ inv1,
                         const int* __restrict__ inv2,
                         int* __restrict__ parent10, int* __restrict__ parent21, int N)
{
    int n = blockIdx.x * blockDim.x + threadIdx.x;
    if (n >= N) return;
    parent10[inv0[n]] = inv1[n];   // duplicate writes all agree (grids nest)
    parent21[inv1[n]] = inv2[n];
}

// ---------------- counting sort: histogram ----------------
__global__ void k_hist(const int* __restrict__ inv0, int* __restrict__ cnt, int N)
{
    int n = blockIdx.x * blockDim.x + threadIdx.x;
    if (n < N) atomicAdd(&cnt[inv0[n]], 1);
}

// ---------------- exclusive scan over MC=4096 bins, single block 1024 thr ----------------
__global__ void k_scan(const int* __restrict__ cnt, int* __restrict__ offs)
{
    __shared__ int arr[1024];
    int tid = threadIdx.x;
    int base = tid * 4;
    int c0 = cnt[base], c1 = cnt[base + 1], c2 = cnt[base + 2], c3 = cnt[base + 3];
    int tot = c0 + c1 + c2 + c3;
    arr[tid] = tot;
    __syncthreads();
    for (int off = 1; off < 1024; off <<= 1) {
        int v = (tid >= off) ? arr[tid - off] : 0;
        __syncthreads();
        arr[tid] += v;
        __syncthreads();
    }
    int excl = arr[tid] - tot;
    offs[base] = excl;
    offs[base + 1] = excl + c0;
    offs[base + 2] = excl + c0 + c1;
    offs[base + 3] = excl + c0 + c1 + c2;
}

// ---------------- placement: order[] groups particles by voxel ----------------
__global__ void k_place(const int* __restrict__ inv0, const int* __restrict__ offs,
                        int* __restrict__ fill, int* __restrict__ order, int N)
{
    int n = blockIdx.x * blockDim.x + threadIdx.x;
    if (n >= N) return;
    int i0 = inv0[n];
    int pos = offs[i0] + atomicAdd(&fill[i0], 1);
    order[pos] = n;
}

// ---------------- pooled sums, no fp atomics: one block per voxel ----------------
__global__ __launch_bounds__(256) void k_pool(const float* __restrict__ h,
                                              const int* __restrict__ order,
                                              const int* __restrict__ offs,
                                              const int* __restrict__ cnt,
                                              float* __restrict__ sum0, float* __restrict__ cnt0,
                                              const int* __restrict__ M0)
{
    int v = blockIdx.x;
    if (v >= *M0) return;
    int beg = offs[v], len = cnt[v];
    int tid = threadIdx.x;
    int d = tid & 127, half = tid >> 7;
    float acc = 0.f;
    for (int j = half; j < len; j += 2) {
        int row = order[beg + j];
        acc += h[(size_t)row * DD + d];
    }
    __shared__ float red[DD];
    if (half == 1) red[d] = acc;
    __syncthreads();
    if (half == 0) {
        acc += red[d];
        sum0[(size_t)v * DD + d] = acc;
        if (d == 0) cnt0[v] = (float)len;
    }
}

// ---------------- roll coarse sums up the hierarchy ----------------
__global__ void k_rollup(const float* __restrict__ sumSrc, const float* __restrict__ cntSrc,
                         const int* __restrict__ parent,
                         float* __restrict__ sumDst, float* __restrict__ cntDst,
                         const int* __restrict__ Msrc, int cap)
{
    int idx = blockIdx.x * blockDim.x + threadIdx.x;   // < cap*DD
    int v = idx >> 7, d = idx & 127;
    int Ms = *Msrc;
    if (Ms > cap) Ms = cap;
    if (v >= Ms) return;
    int p = parent[v];
    atomicAdd(&sumDst[(size_t)p * DD + d], sumSrc[idx]);
    if (d == 0) atomicAdd(&cntDst[p], cntSrc[v]);
}

// ---------------- divide by clamped counts ----------------
__global__ void k_finalize(float* __restrict__ macro, const float* __restrict__ counts,
                           const int* M0, const int* M1, const int* M2)
{
    int idx = blockIdx.x * blockDim.x + threadIdx.x;  // < NS*MC*DD
    int s = idx / (MC * DD);
    int r = (idx >> 7) & (MC - 1);
    if (r >= getM(s, M0, M1, M2)) return;
    float c = counts[s * MC + r];
    macro[idx] /= fmaxf(c, 1.0f);
}

// ---------------- B0T[k][d] = Wf[d][k] ----------------
__global__ void k_b0t(const float* __restrict__ Wf, float* __restrict__ B0T)
{
    int idx = blockIdx.x * 256 + threadIdx.x;  // 16384
    int k = idx >> 7, d = idx & 127;
    B0T[idx] = Wf[(size_t)d * (4 * DD) + k];
}

// ---------------- qkv = macro @ Wqkv[s].T + bqkv[s], 8 rows/block ----------------
__global__ void k_qkv(const float* __restrict__ macro, const float* __restrict__ Wqkv,
                      const float* __restrict__ bqkv, float* __restrict__ qkv,
                      const int* M0, const int* M1, const int* M2)
{
    int s = blockIdx.y;
    int Ms = getM(s, M0, M1, M2);
    int row0 = blockIdx.x * 8;
    if (row0 >= Ms) return;
    __shared__ __align__(16) float mac[8][DD];
    int tid = threadIdx.x;
    for (int e = tid; e < 8 * DD; e += 256) {
        int r = e >> 7, d = e & 127;
        int row = row0 + r;
        mac[r][d] = (row < Ms) ? macro[(size_t)s * MC * DD + (size_t)row * DD + d] : 0.0f;
    }
    __syncthreads();
    for (int j = tid; j < 3 * DD; j += 256) {
        const float* w = Wqkv + ((size_t)s * 3 * DD + j) * DD;
        float b = bqkv[s * 3 * DD + j];
        float acc[8];
#pragma unroll
        for (int r = 0; r < 8; ++r) acc[r] = b;
        for (int k = 0; k < DD; k += 4) {
            float4 w4 = *(const float4*)(w + k);
#pragma unroll
            for (int r = 0; r < 8; ++r) {
                float4 m4 = *(const float4*)&mac[r][k];
                acc[r] += w4.x * m4.x + w4.y * m4.y + w4.z * m4.z + w4.w * m4.w;
            }
        }
        for (int r = 0; r < 8; ++r) {
            int row = row0 + r;
            if (row < Ms) qkv[((size_t)s * MC + row) * (3 * DD) + j] = acc[r];
        }
    }
}

// ---------------- flash attention partials: no LDS, no barriers ----------------
// thread = (query row qi, key-quarter sub); q/o/p in registers; K/V via L1.
__global__ __launch_bounds__(256) void k_attn_part(const float* __restrict__ qkv,
                                                   float* __restrict__ part_o,
                                                   float* __restrict__ part_ml,
                                                   const int* M0, const int* M1, const int* M2)
{
    int z = blockIdx.z;
    int s = z / NSPLIT, part = z % NSPLIT;
    int head = blockIdx.y;
    int Ms = getM(s, M0, M1, M2);
    int q0 = blockIdx.x * 64;
    if (q0 >= Ms) return;
    int kstart = part * PLEN;
    if (kstart >= Ms) return;
    int kend = kstart + PLEN; if (kend > Ms) kend = Ms;

    int tid = threadIdx.x;
    int qi = tid >> 2, sub = tid & 3;
    int qrow = q0 + qi;

    const float* base = qkv + (size_t)s * MC * 3 * DD;
    const float* Qb = base + head * DH;
    const float* Kb = base + DD + head * DH;
    const float* Vb = base + 2 * DD + head * DH;

    float4 q4[8];
#pragma unroll
    for (int r = 0; r < 8; ++r) q4[r] = make_float4(0.f, 0.f, 0.f, 0.f);
    if (qrow < Ms) {
#pragma unroll
        for (int r = 0; r < 8; ++r) q4[r] = *(const float4*)(Qb + (size_t)qrow * 3 * DD + r * 4);
    }

    float4 o4[8];
#pragma unroll
    for (int r = 0; r < 8; ++r) o4[r] = make_float4(0.f, 0.f, 0.f, 0.f);
    float m = -1e30f, l = 0.f;
    const float scale = 0.1767766952966369f;  // 1/sqrt(32)

    for (int kb = kstart; kb < kend; kb += 64) {
        float p[16];
#pragma unroll 4
        for (int j = 0; j < 16; ++j) {
            int key = kb + j * 4 + sub;
            float sc = -1e30f;
            if (key < kend) {
                const float* kr = Kb + (size_t)key * 3 * DD;
                float acc = 0.f;
#pragma unroll
                for (int r = 0; r < 8; ++r) {
                    float4 kv = *(const float4*)(kr + r * 4);
                    acc += q4[r].x * kv.x + q4[r].y * kv.y + q4[r].z * kv.z + q4[r].w * kv.w;
                }
                sc = acc * scale;
            }
            p[j] = sc;
        }
        float lmax = p[0];
#pragma unroll
        for (int j = 1; j < 16; ++j) lmax = fmaxf(lmax, p[j]);
        lmax = fmaxf(lmax, __shfl_xor(lmax, 1));
        lmax = fmaxf(lmax, __shfl_xor(lmax, 2));
        float mnew = fmaxf(m, lmax);
        float alpha = __expf(m - mnew);
        m = mnew;
        l *= alpha;
#pragma unroll
        for (int r = 0; r < 8; ++r) {
            o4[r].x *= alpha; o4[r].y *= alpha; o4[r].z *= alpha; o4[r].w *= alpha;
        }
        float lsum = 0.f;
#pragma unroll
        for (int j = 0; j < 16; ++j) {
            float e = __expf(p[j] - mnew);
            p[j] = e;
            lsum += e;
        }
#pragma unroll 4
        for (int j = 0; j < 16; ++j) {
            int key = kb + j * 4 + sub;
            if (key < kend) {
                const float* vr = Vb + (size_t)key * 3 * DD;
                float pv = p[j];
#pragma unroll
                for (int r = 0; r < 8; ++r) {
                    float4 vv = *(const float4*)(vr + r * 4);
                    o4[r].x += pv * vv.x; o4[r].y += pv * vv.y;
                    o4[r].z += pv * vv.z; o4[r].w += pv * vv.w;
                }
            }
        }
        lsum += __shfl_xor(lsum, 1);
        lsum += __shfl_xor(lsum, 2);
        l += lsum;
    }

    // reduce o across the 4 subs (all end with identical full o)
#pragma unroll
    for (int r = 0; r < 8; ++r) {
        o4[r].x += __shfl_xor(o4[r].x, 1); o4[r].y += __shfl_xor(o4[r].y, 1);
        o4[r].z += __shfl_xor(o4[r].z, 1); o4[r].w += __shfl_xor(o4[r].w, 1);
        o4[r].x += __shfl_xor(o4[r].x, 2); o4[r].y += __shfl_xor(o4[r].y, 2);
        o4[r].z += __shfl_xor(o4[r].z, 2); o4[r].w += __shfl_xor(o4[r].w, 2);
    }

    int rec = ((s * NHH + head) * 64 + blockIdx.x) * NSPLIT + part;
    float* po = part_o + (size_t)rec * 2048;
    // each sub writes its 8-float slice of the 32-dim output
    *(float4*)(po + qi * 32 + sub * 8)     = o4[2 * sub];
    *(float4*)(po + qi * 32 + sub * 8 + 4) = o4[2 * sub + 1];
    if (sub == 0) {
        part_ml[rec * 128 + qi] = m;
        part_ml[rec * 128 + 64 + qi] = l;
    }
}

// ---------------- merge split-K partials ----------------
__global__ void k_attn_comb(const float* __restrict__ part_o, const float* __restrict__ part_ml,
                            float* __restrict__ attno,
                            const int* M0, const int* M1, const int* M2)
{
    int s = blockIdx.z, head = blockIdx.y;
    int Ms = getM(s, M0, M1, M2);
    int q0 = blockIdx.x * 64;
    if (q0 >= Ms) return;
    int tid = threadIdx.x;
    int qi = tid >> 2, sub = tid & 3;
    int nparts = (Ms + PLEN - 1) / PLEN;
    if (nparts > NSPLIT) nparts = NSPLIT;
    int recbase = ((s * NHH + head) * 64 + blockIdx.x) * NSPLIT;

    float m = -1e30f;
    for (int p = 0; p < nparts; ++p)
        m = fmaxf(m, part_ml[(recbase + p) * 128 + qi]);
    float L = 0.f;
    float4 O0 = make_float4(0.f, 0.f, 0.f, 0.f);
    float4 O1 = make_float4(0.f, 0.f, 0.f, 0.f);
    for (int p = 0; p < nparts; ++p) {
        float mp = part_ml[(recbase + p) * 128 + qi];
        float lp = part_ml[(recbase + p) * 128 + 64 + qi];
        float w = __expf(mp - m);
        L += lp * w;
        const float* po = part_o + (size_t)(recbase + p) * 2048;
        float4 a = *(const float4*)(po + qi * 32 + sub * 4);
        float4 b = *(const float4*)(po + qi * 32 + (sub + 4) * 4);
        O0.x += a.x * w; O0.y += a.y * w; O0.z += a.z * w; O0.w += a.w * w;
        O1.x += b.x * w; O1.y += b.y * w; O1.z += b.z * w; O1.w += b.w * w;
    }
    if (q0 + qi < Ms) {
        float inv = 1.0f / fmaxf(L, 1e-30f);
        size_t orow = ((size_t)s * MC + q0 + qi) * DD + head * DH;
        float4 r0 = make_float4(O0.x * inv, O0.y * inv, O0.z * inv, O0.w * inv);
        float4 r1 = make_float4(O1.x * inv, O1.y * inv, O1.z * inv, O1.w * inv);
        *(float4*)(attno + orow + sub * 4) = r0;
        *(float4*)(attno + orow + (sub + 4) * 4) = r1;
    }
}

// ---------------- x1 = LN1(macro + attno @ Wo.T + bo) ----------------
__global__ void k_ln1(const float* __restrict__ macro, const float* __restrict__ attno,
                      const float* __restrict__ Wo, const float* __restrict__ bo,
                      const float* __restrict__ g, const float* __restrict__ b,
                      float* __restrict__ x1,
                      const int* M0, const int* M1, const int* M2)
{
    int s = blockIdx.y;
    int Ms = getM(s, M0, M1, M2);
    int m = blockIdx.x;
    if (m >= Ms) return;
    __shared__ __align__(16) float os[DD];
    __shared__ float red[4];
    int d = threadIdx.x;  // 128
    size_t row = (size_t)s * MC + m;
    os[d] = attno[row * DD + d];
    __syncthreads();
    const float* w = Wo + ((size_t)s * DD + d) * DD;
    float acc = bo[s * DD + d];
    for (int k = 0; k < DD; k += 4) {
        float4 w4 = *(const float4*)(w + k);
        float4 m4 = *(const float4*)&os[k];
        acc += w4.x * m4.x + w4.y * m4.y + w4.z * m4.z + w4.w * m4.w;
    }
    float xin = macro[row * DD + d] + acc;
    float sum = xin, sq = xin * xin;
    for (int off = 32; off >= 1; off >>= 1) { sum += __shfl_xor(sum, off); sq += __shfl_xor(sq, off); }
    if ((d & 63) == 0) { red[d >> 6] = sum; red[2 + (d >> 6)] = sq; }
    __syncthreads();
    sum = red[0] + red[1]; sq = red[2] + red[3];
    float mean = sum * (1.0f / DD);
    float var = fmaxf(sq * (1.0f / DD) - mean * mean, 0.0f);
    float xh = (xin - mean) * rsqrtf(var + 1e-5f);
    x1[row * DD + d] = xh * g[s * DD + d] + b[s * DD + d];
}

// ---------------- x2 = LN2(x1 + relu(x1@W1.T+b1)@W2.T + b2) ----------------
__global__ void k_ffn(const float* __restrict__ x1,
                      const float* __restrict__ W1, const float* __restrict__ b1,
                      const float* __restrict__ W2, const float* __restrict__ b2,
                      const float* __restrict__ g, const float* __restrict__ bb,
                      float* __restrict__ x2,
                      const int* M0, const int* M1, const int* M2)
{
    int s = blockIdx.y;
    int Ms = getM(s, M0, M1, M2);
    int m = blockIdx.x;
    if (m >= Ms) return;
    __shared__ __align__(16) float xr[DD];
    __shared__ __align__(16) float ts[FFD];
    __shared__ float red[8];
    int tid = threadIdx.x;  // 256
    size_t row = (size_t)s * MC + m;
    if (tid < DD) xr[tid] = x1[row * DD + tid];
    __syncthreads();
    {
        const float* w = W1 + ((size_t)s * FFD + tid) * DD;
        float acc = b1[s * FFD + tid];
        for (int k = 0; k < DD; k += 4) {
            float4 w4 = *(const float4*)(w + k);
            float4 m4 = *(const float4*)&xr[k];
            acc += w4.x * m4.x + w4.y * m4.y + w4.z * m4.z + w4.w * m4.w;
        }
        ts[tid] = fmaxf(acc, 0.0f);
    }
    __syncthreads();
    float xin = 0.0f;
    if (tid < DD) {
        const float* w = W2 + ((size_t)s * DD + tid) * FFD;
        float acc = b2[s * DD + tid];
        for (int k = 0; k < FFD; k += 4) {
            float4 w4 = *(const float4*)(w + k);
            float4 m4 = *(const float4*)&ts[k];
            acc += w4.x * m4.x + w4.y * m4.y + w4.z * m4.z + w4.w * m4.w;
        }
        xin = xr[tid] + acc;
    }
    float sum = xin, sq = xin * xin;
    for (int off = 32; off >= 1; off >>= 1) { sum += __shfl_xor(sum, off); sq += __shfl_xor(sq, off); }
    if ((tid & 63) == 0) { red[tid >> 6] = sum; red[4 + (tid >> 6)] = sq; }
    __syncthreads();
    sum = red[0] + red[1] + red[2] + red[3];
    sq = red[4] + red[5] + red[6] + red[7];
    float mean = sum * (1.0f / DD);
    float var = fmaxf(sq * (1.0f / DD) - mean * mean, 0.0f);
    if (tid < DD) {
        float xh = (xin - mean) * rsqrtf(var + 1e-5f);
        x2[row * DD + tid] = xh * g[s * DD + tid] + bb[s * DD + tid];
    }
}

// ---------------- y_s = x2_s @ Wf[:, 128*(s+1):128*(s+2)].T ----------------
__global__ void k_yproj(const float* __restrict__ x2, const float* __restrict__ Wf,
                        float* __restrict__ y,
                        const int* M0, const int* M1, const int* M2)
{
    int s = blockIdx.y;
    int Ms = getM(s, M0, M1, M2);
    int m = blockIdx.x;
    if (m >= Ms) return;
    __shared__ __align__(16) float xr[DD];
    int d = threadIdx.x;  // 128
    size_t row = (size_t)s * MC + m;
    xr[d] = x2[row * DD + d];
    __syncthreads();
    const float* w = Wf + (size_t)d * (4 * DD) + (s + 1) * DD;
    float acc = 0.0f;
    for (int k = 0; k < DD; k += 4) {
        float4 w4 = *(const float4*)(w + k);
        float4 m4 = *(const float4*)&xr[k];
        acc += w4.x * m4.x + w4.y * m4.y + w4.z * m4.z + w4.w * m4.w;
    }
    y[row * DD + d] = acc;
}

// ---------------- out = h@B0 + y0[inv0] + y1[inv1] + y2[inv2] + bf ----------------
__global__ __launch_bounds__(256) void k_final(const float* __restrict__ h,
                                               const float* __restrict__ B0T,
                                               const float* __restrict__ y,
                                               const int* __restrict__ inv0,
                                               const int* __restrict__ inv1,
                                               const int* __restrict__ inv2,
                                               const float* __restrict__ bf,
                                               float* __restrict__ out, int N)
{
    __shared__ __align__(16) float hs[64][132];
    int tid = threadIdx.x;
    int ntiles = (N + 63) >> 6;
    const float* y0 = y;
    const float* y1 = y + (size_t)MC * DD;
    const float* y2 = y + (size_t)2 * MC * DD;
    for (int t = blockIdx.x; t < ntiles; t += gridDim.x) {
        int pb = t * 64;
        __syncthreads();
        for (int fq = tid; fq < 64 * 32; fq += 256) {
            int p = fq >> 5, q = fq & 31;
            float4 v4 = make_float4(0.f, 0.f, 0.f, 0.f);
            if (pb + p < N) v4 = *(const float4*)(h + ((size_t)(pb + p)) * DD + q * 4);
            *(float4*)&hs[p][q * 4] = v4;
        }
        __syncthreads();
        int pg = tid & 15, dg = tid >> 4;
        int d0 = dg * 8;
        float4 a0[4], a1[4];
#pragma unroll
        for (int i = 0; i < 4; ++i) {
            a0[i] = make_float4(0.f, 0.f, 0.f, 0.f);
            a1[i] = make_float4(0.f, 0.f, 0.f, 0.f);
        }
        for (int k = 0; k < DD; k += 4) {
            float4 h4[4];
#pragma unroll
            for (int i = 0; i < 4; ++i) h4[i] = *(const float4*)&hs[pg + 16 * i][k];
#pragma unroll
            for (int kk = 0; kk < 4; ++kk) {
                float4 ba = *(const float4*)(B0T + (size_t)(k + kk) * DD + d0);
                float4 bb = *(const float4*)(B0T + (size_t)(k + kk) * DD + d0 + 4);
#pragma unroll
                for (int i = 0; i < 4; ++i) {
                    float hv = (kk == 0) ? h4[i].x : (kk == 1) ? h4[i].y : (kk == 2) ? h4[i].z : h4[i].w;
                    a0[i].x += hv * ba.x; a0[i].y += hv * ba.y; a0[i].z += hv * ba.z; a0[i].w += hv * ba.w;
                    a1[i].x += hv * bb.x; a1[i].y += hv * bb.y; a1[i].z += hv * bb.z; a1[i].w += hv * bb.w;
                }
            }
        }
        float4 bf0 = *(const float4*)(bf + d0);
        float4 bf1 = *(const float4*)(bf + d0 + 4);
#pragma unroll
        for (int i = 0; i < 4; ++i) {
            int p = pb + pg + 16 * i;
            if (p >= N) continue;
            int i0 = inv0[p], i1 = inv1[p], i2 = inv2[p];
            float4 g0 = *(const float4*)(y0 + (size_t)i0 * DD + d0);
            float4 g0b = *(const float4*)(y0 + (size_t)i0 * DD + d0 + 4);
            float4 g1 = *(const float4*)(y1 + (size_t)i1 * DD + d0);
            float4 g1b = *(const float4*)(y1 + (size_t)i1 * DD + d0 + 4);
            float4 g2 = *(const float4*)(y2 + (size_t)i2 * DD + d0);
            float4 g2b = *(const float4*)(y2 + (size_t)i2 * DD + d0 + 4);
            float4 r0 = make_float4(a0[i].x + g0.x + g1.x + g2.x + bf0.x,
                                    a0[i].y + g0.y + g1.y + g2.y + bf0.y,
                                    a0[i].z + g0.z + g1.z + g2.z + bf0.z,
                                    a0[i].w + g0.w + g1.w + g2.w + bf0.w);
            float4 r1 = make_float4(a1[i].x + g0b.x + g1b.x + g2b.x + bf1.x,
                                    a1[i].y + g0b.y + g1b.y + g2b.y + bf1.y,
                                    a1[i].z + g0b.z + g1b.z + g2b.z + bf1.z,
                                    a1[i].w + g0b.w + g1b.w + g2b.w + bf1.w);
            *(float4*)(out + (size_t)p * DD + d0) = r0;
            *(float4*)(out + (size_t)p * DD + d0 + 4) = r1;
        }
    }
}

extern "C" void kernel_launch(void* const* d_in, const int* in_sizes, int n_in,
                              void* d_out, int out_size, void* d_ws, size_t ws_size,
                              hipStream_t stream) {
    (void)n_in; (void)out_size; (void)ws_size;
    const float* h   = (const float*)d_in[0];
    const int* inv0  = (const int*)d_in[2];
    const int* inv1  = (const int*)d_in[3];
    const int* inv2  = (const int*)d_in[4];
    const int* M0    = (const int*)d_in[5];
    const int* M1    = (const int*)d_in[6];
    const int* M2    = (const int*)d_in[7];
    const float* Wqkv = (const float*)d_in[8];
    const float* bqkv = (const float*)d_in[9];
    const float* Wo   = (const float*)d_in[10];
    const float* bo   = (const float*)d_in[11];
    const float* ln1s = (const float*)d_in[12];
    const float* ln1b = (const float*)d_in[13];
    const float* W1   = (const float*)d_in[14];
    const float* b1   = (const float*)d_in[15];
    const float* W2   = (const float*)d_in[16];
    const float* b2   = (const float*)d_in[17];
    const float* ln2s = (const float*)d_in[18];
    const float* ln2b = (const float*)d_in[19];
    const float* Wf   = (const float*)d_in[20];
    const float* bf   = (const float*)d_in[21];
    int N = in_sizes[0] / DD;

    float* ws      = (float*)d_ws;
    float* macro   = ws;                                    // NS*MC*DD
    float* counts  = macro + (size_t)NS * MC * DD;          // NS*MC
    float* qkvb    = counts + (size_t)NS * MC;              // NS*MC*3*DD
    float* attno   = qkvb + (size_t)NS * MC * 3 * DD;       // NS*MC*DD
    float* x1      = attno + (size_t)NS * MC * DD;          // NS*MC*DD
    float* x2      = x1 + (size_t)NS * MC * DD;             // NS*MC*DD
    float* yb      = x2 + (size_t)NS * MC * DD;             // NS*MC*DD
    float* B0T     = yb + (size_t)NS * MC * DD;             // DD*DD
    float* part_o  = B0T + (size_t)DD * DD;                 // NS*NHH*64*NSPLIT*2048
    float* part_ml = part_o + (size_t)NS * NHH * 64 * NSPLIT * 2048;  // NS*NHH*64*NSPLIT*128
    int* ip        = (int*)(part_ml + (size_t)NS * NHH * 64 * NSPLIT * 128);
    int* parent10  = ip;                // MC
    int* parent21  = parent10 + MC;     // 512
    int* cnt_i     = parent21 + 512;    // MC
    int* fill      = cnt_i + MC;        // MC
    int* offs      = fill + MC;         // MC
    int* order     = offs + MC;         // N

    float* sum0 = macro;
    float* sum1 = macro + (size_t)1 * MC * DD;
    float* sum2 = macro + (size_t)2 * MC * DD;
    float* cnt0 = counts;
    float* cnt1 = counts + MC;
    float* cnt2 = counts + 2 * MC;

    hipMemsetAsync(macro, 0, ((size_t)NS * MC * DD + NS * MC) * sizeof(float), stream);
    hipMemsetAsync(cnt_i, 0, (size_t)2 * MC * sizeof(int), stream);

    int nb = (N + 255) / 256;
    k_parent<<<nb, 256, 0, stream>>>(inv0, inv1, inv2, parent10, parent21, N);
    k_hist<<<nb, 256, 0, stream>>>(inv0, cnt_i, N);
    k_scan<<<1, 1024, 0, stream>>>(cnt_i, offs);
    k_place<<<nb, 256, 0, stream>>>(inv0, offs, fill, order, N);
    k_pool<<<MC, 256, 0, stream>>>(h, order, offs, cnt_i, sum0, cnt0, M0);
    k_rollup<<<(MC * DD) / 256, 256, 0, stream>>>(sum0, cnt0, parent10, sum1, cnt1, M0, MC);
    k_rollup<<<(512 * DD) / 256, 256, 0, stream>>>(sum1, cnt1, parent21, sum2, cnt2, M1, 512);
    k_finalize<<<(NS * MC * DD) / 256, 256, 0, stream>>>(macro, counts, M0, M1, M2);
    k_b0t<<<64, 256, 0, stream>>>(Wf, B0T);
    k_qkv<<<dim3(MC / 8, NS), 256, 0, stream>>>(macro, Wqkv, bqkv, qkvb, M0, M1, M2);
    k_attn_part<<<dim3(MC / 64, NHH, NS * NSPLIT), 256, 0, stream>>>(qkvb, part_o, part_ml, M0, M1, M2);
    k_attn_comb<<<dim3(MC / 64, NHH, NS), 256, 0, stream>>>(part_o, part_ml, attno, M0, M1, M2);
    k_ln1<<<dim3(MC, NS), 128, 0, stream>>>(macro, attno, Wo, bo, ln1s, ln1b, x1, M0, M1, M2);
    k_ffn<<<dim3(MC, NS), 256, 0, stream>>>(x1, W1, b1, W2, b2, ln2s, ln2b, x2, M0, M1, M2);
    k_yproj<<<dim3(MC, NS), 128, 0, stream>>>(x2, Wf, yb, M0, M1, M2);
    k_final<<<2048, 256, 0, stream>>>(h, B0T, yb, inv0, inv1, inv2, bf, (float*)d_out, N);
}

// Round 5
// 1144.143 us; speedup vs baseline: 2.5309x; 2.5309x over previous
//
#include <hip/hip_runtime.h>
#include <hip/hip_bf16.h>

#define MC 4096
#define DD 128
#define NHH 4
#define DH 32
#define FFD 256
#define NS 3
#define NSPLIT 4
#define PLEN 1024

__device__ __forceinline__ int getM(int s, const int* M0, const int* M1, const int* M2) {
    return (s == 0) ? *M0 : (s == 1) ? *M1 : *M2;
}

// ---------------- parent maps + scale-0 histogram in one pass ----------------
__global__ void k_parent(const int* __restrict__ inv0, const int* __restrict__ inv1,
                         const int* __restrict__ inv2,
                         int* __restrict__ parent10, int* __restrict__ parent21,
                         int* __restrict__ cnt, int N)
{
    int n = blockIdx.x * blockDim.x + threadIdx.x;
    if (n >= N) return;
    int i0 = inv0[n];
    parent10[i0] = inv1[n];   // duplicate writes all agree (grids nest)
    parent21[inv1[n]] = inv2[n];
    atomicAdd(&cnt[i0], 1);
}

// ---------------- exclusive scan over MC=4096 bins, single block 1024 thr ----------------
__global__ void k_scan(const int* __restrict__ cnt, int* __restrict__ offs)
{
    __shared__ int arr[1024];
    int tid = threadIdx.x;
    int base = tid * 4;
    int c0 = cnt[base], c1 = cnt[base + 1], c2 = cnt[base + 2], c3 = cnt[base + 3];
    int tot = c0 + c1 + c2 + c3;
    arr[tid] = tot;
    __syncthreads();
    for (int off = 1; off < 1024; off <<= 1) {
        int v = (tid >= off) ? arr[tid - off] : 0;
        __syncthreads();
        arr[tid] += v;
        __syncthreads();
    }
    int excl = arr[tid] - tot;
    offs[base] = excl;
    offs[base + 1] = excl + c0;
    offs[base + 2] = excl + c0 + c1;
    offs[base + 3] = excl + c0 + c1 + c2;
}

// ---------------- placement: order[] groups particles by voxel ----------------
__global__ void k_place(const int* __restrict__ inv0, const int* __restrict__ offs,
                        int* __restrict__ fill, int* __restrict__ order, int N)
{
    int n = blockIdx.x * blockDim.x + threadIdx.x;
    if (n >= N) return;
    int i0 = inv0[n];
    int pos = offs[i0] + atomicAdd(&fill[i0], 1);
    order[pos] = n;
}

// ---------------- pooled sums, no fp atomics: one block per voxel ----------------
__global__ __launch_bounds__(256) void k_pool(const float* __restrict__ h,
                                              const int* __restrict__ order,
                                              const int* __restrict__ offs,
                                              const int* __restrict__ cnt,
                                              float* __restrict__ sum0, float* __restrict__ cnt0,
                                              const int* __restrict__ M0)
{
    int v = blockIdx.x;
    if (v >= *M0) return;
    int beg = offs[v], len = cnt[v];
    int tid = threadIdx.x;
    int d = tid & 127, half = tid >> 7;
    float acc = 0.f;
    for (int j = half; j < len; j += 2) {
        int row = order[beg + j];
        acc += h[(size_t)row * DD + d];
    }
    __shared__ float red[DD];
    if (half == 1) red[d] = acc;
    __syncthreads();
    if (half == 0) {
        acc += red[d];
        sum0[(size_t)v * DD + d] = acc;
        if (d == 0) cnt0[v] = (float)len;
    }
}

// ---------------- roll coarse sums up the hierarchy ----------------
__global__ void k_rollup(const float* __restrict__ sumSrc, const float* __restrict__ cntSrc,
                         const int* __restrict__ parent,
                         float* __restrict__ sumDst, float* __restrict__ cntDst,
                         const int* __restrict__ Msrc, int cap)
{
    int idx = blockIdx.x * blockDim.x + threadIdx.x;   // < cap*DD
    int v = idx >> 7, d = idx & 127;
    int Ms = *Msrc;
    if (Ms > cap) Ms = cap;
    if (v >= Ms) return;
    int p = parent[v];
    atomicAdd(&sumDst[(size_t)p * DD + d], sumSrc[idx]);
    if (d == 0) atomicAdd(&cntDst[p], cntSrc[v]);
}

// ---------------- divide by clamped counts ----------------
__global__ void k_finalize(float* __restrict__ macro, const float* __restrict__ counts,
                           const int* M0, const int* M1, const int* M2)
{
    int idx = blockIdx.x * blockDim.x + threadIdx.x;  // < NS*MC*DD
    int s = idx / (MC * DD);
    int r = (idx >> 7) & (MC - 1);
    if (r >= getM(s, M0, M1, M2)) return;
    float c = counts[s * MC + r];
    macro[idx] /= fmaxf(c, 1.0f);
}

// ---------------- B0T[k][d] = Wf[d][k] ----------------
__global__ void k_b0t(const float* __restrict__ Wf, float* __restrict__ B0T)
{
    int idx = blockIdx.x * 256 + threadIdx.x;  // 16384
    int k = idx >> 7, d = idx & 127;
    B0T[idx] = Wf[(size_t)d * (4 * DD) + k];
}

// ---------------- qkv = macro @ Wqkv[s].T + bqkv[s], 8 rows/block ----------------
__global__ void k_qkv(const float* __restrict__ macro, const float* __restrict__ Wqkv,
                      const float* __restrict__ bqkv, float* __restrict__ qkv,
                      const int* M0, const int* M1, const int* M2)
{
    int s = blockIdx.y;
    int Ms = getM(s, M0, M1, M2);
    int row0 = blockIdx.x * 8;
    if (row0 >= Ms) return;
    __shared__ __align__(16) float mac[8][DD];
    int tid = threadIdx.x;
    for (int e = tid; e < 8 * DD; e += 256) {
        int r = e >> 7, d = e & 127;
        int row = row0 + r;
        mac[r][d] = (row < Ms) ? macro[(size_t)s * MC * DD + (size_t)row * DD + d] : 0.0f;
    }
    __syncthreads();
    for (int j = tid; j < 3 * DD; j += 256) {
        const float* w = Wqkv + ((size_t)s * 3 * DD + j) * DD;
        float b = bqkv[s * 3 * DD + j];
        float acc[8];
#pragma unroll
        for (int r = 0; r < 8; ++r) acc[r] = b;
        for (int k = 0; k < DD; k += 4) {
            float4 w4 = *(const float4*)(w + k);
#pragma unroll
            for (int r = 0; r < 8; ++r) {
                float4 m4 = *(const float4*)&mac[r][k];
                acc[r] += w4.x * m4.x + w4.y * m4.y + w4.z * m4.z + w4.w * m4.w;
            }
        }
        for (int r = 0; r < 8; ++r) {
            int row = row0 + r;
            if (row < Ms) qkv[((size_t)s * MC + row) * (3 * DD) + j] = acc[r];
        }
    }
}

// ---------------- flash attention partials: LDS-staged K/V, register p/m/l/o ----------------
// thread = (query row qi, key-quarter sub). K/V staged cooperatively (coalesced),
// read back as 16-lane broadcasts (free). Softmax via 4-lane shfl. 2 barriers/chunk.
__global__ __launch_bounds__(256) void k_attn_part(const float* __restrict__ qkv,
                                                   float* __restrict__ part_o,
                                                   float* __restrict__ part_ml,
                                                   const int* M0, const int* M1, const int* M2)
{
    int z = blockIdx.z;
    int s = z / NSPLIT, part = z % NSPLIT;
    int head = blockIdx.y;
    int Ms = getM(s, M0, M1, M2);
    int q0 = blockIdx.x * 64;
    if (q0 >= Ms) return;
    int kstart = part * PLEN;
    if (kstart >= Ms) return;
    int kend = kstart + PLEN; if (kend > Ms) kend = Ms;

    __shared__ __align__(16) float ks[64][36];
    __shared__ __align__(16) float vs[64][36];

    int tid = threadIdx.x;
    int qi = tid >> 2, sub = tid & 3;
    int qrow = q0 + qi;

    const float* base = qkv + (size_t)s * MC * 3 * DD;
    const float* Qb = base + head * DH;
    const float* Kb = base + DD + head * DH;
    const float* Vb = base + 2 * DD + head * DH;

    float4 q4[8];
#pragma unroll
    for (int r = 0; r < 8; ++r) q4[r] = make_float4(0.f, 0.f, 0.f, 0.f);
    if (qrow < Ms) {
#pragma unroll
        for (int r = 0; r < 8; ++r) q4[r] = *(const float4*)(Qb + (size_t)qrow * 3 * DD + r * 4);
    }

    float4 o4[8];
#pragma unroll
    for (int r = 0; r < 8; ++r) o4[r] = make_float4(0.f, 0.f, 0.f, 0.f);
    float m = -1e30f, l = 0.f;
    const float scale = 0.1767766952966369f;  // 1/sqrt(32)

    for (int kb = kstart; kb < kend; kb += 64) {
        __syncthreads();   // previous chunk's readers done
        for (int e = tid; e < 64 * 8; e += 256) {
            int r = e >> 3, qq = e & 7;
            int key = kb + r;
            float4 kv4 = make_float4(0.f, 0.f, 0.f, 0.f);
            float4 vv4 = make_float4(0.f, 0.f, 0.f, 0.f);
            if (key < kend) {
                kv4 = *(const float4*)(Kb + (size_t)key * 3 * DD + qq * 4);
                vv4 = *(const float4*)(Vb + (size_t)key * 3 * DD + qq * 4);
            }
            *(float4*)&ks[r][qq * 4] = kv4;
            *(float4*)&vs[r][qq * 4] = vv4;
        }
        __syncthreads();

        float p[16];
#pragma unroll 4
        for (int j = 0; j < 16; ++j) {
            int kk = j * 4 + sub;                 // interleaved: pad-36 keeps banks distinct
            float acc = 0.f;
#pragma unroll
            for (int r = 0; r < 8; ++r) {
                float4 kv = *(const float4*)&ks[kk][r * 4];
                acc += q4[r].x * kv.x + q4[r].y * kv.y + q4[r].z * kv.z + q4[r].w * kv.w;
            }
            p[j] = (kb + kk < kend) ? acc * scale : -1e30f;
        }
        float lmax = p[0];
#pragma unroll
        for (int j = 1; j < 16; ++j) lmax = fmaxf(lmax, p[j]);
        lmax = fmaxf(lmax, __shfl_xor(lmax, 1));
        lmax = fmaxf(lmax, __shfl_xor(lmax, 2));
        float mnew = fmaxf(m, lmax);
        float alpha = __expf(m - mnew);
        m = mnew;
        l *= alpha;
#pragma unroll
        for (int r = 0; r < 8; ++r) {
            o4[r].x *= alpha; o4[r].y *= alpha; o4[r].z *= alpha; o4[r].w *= alpha;
        }
        float lsum = 0.f;
#pragma unroll
        for (int j = 0; j < 16; ++j) {
            float e = __expf(p[j] - mnew);
            p[j] = e;
            lsum += e;
        }
#pragma unroll 4
        for (int j = 0; j < 16; ++j) {
            int kk = j * 4 + sub;
            float pv = p[j];
#pragma unroll
            for (int r = 0; r < 8; ++r) {
                float4 vv = *(const float4*)&vs[kk][r * 4];
                o4[r].x += pv * vv.x; o4[r].y += pv * vv.y;
                o4[r].z += pv * vv.z; o4[r].w += pv * vv.w;
            }
        }
        lsum += __shfl_xor(lsum, 1);
        lsum += __shfl_xor(lsum, 2);
        l += lsum;
    }

    // reduce o across the 4 subs
#pragma unroll
    for (int r = 0; r < 8; ++r) {
        o4[r].x += __shfl_xor(o4[r].x, 1); o4[r].y += __shfl_xor(o4[r].y, 1);
        o4[r].z += __shfl_xor(o4[r].z, 1); o4[r].w += __shfl_xor(o4[r].w, 1);
        o4[r].x += __shfl_xor(o4[r].x, 2); o4[r].y += __shfl_xor(o4[r].y, 2);
        o4[r].z += __shfl_xor(o4[r].z, 2); o4[r].w += __shfl_xor(o4[r].w, 2);
    }

    int rec = ((s * NHH + head) * 64 + blockIdx.x) * NSPLIT + part;
    float* po = part_o + (size_t)rec * 2048;
    *(float4*)(po + qi * 32 + sub * 8)     = o4[2 * sub];
    *(float4*)(po + qi * 32 + sub * 8 + 4) = o4[2 * sub + 1];
    if (sub == 0) {
        part_ml[rec * 128 + qi] = m;
        part_ml[rec * 128 + 64 + qi] = l;
    }
}

// ---------------- merge split-K partials ----------------
__global__ void k_attn_comb(const float* __restrict__ part_o, const float* __restrict__ part_ml,
                            float* __restrict__ attno,
                            const int* M0, const int* M1, const int* M2)
{
    int s = blockIdx.z, head = blockIdx.y;
    int Ms = getM(s, M0, M1, M2);
    int q0 = blockIdx.x * 64;
    if (q0 >= Ms) return;
    int tid = threadIdx.x;
    int qi = tid >> 2, sub = tid & 3;
    int nparts = (Ms + PLEN - 1) / PLEN;
    if (nparts > NSPLIT) nparts = NSPLIT;
    int recbase = ((s * NHH + head) * 64 + blockIdx.x) * NSPLIT;

    float m = -1e30f;
    for (int p = 0; p < nparts; ++p)
        m = fmaxf(m, part_ml[(recbase + p) * 128 + qi]);
    float L = 0.f;
    float4 O0 = make_float4(0.f, 0.f, 0.f, 0.f);
    float4 O1 = make_float4(0.f, 0.f, 0.f, 0.f);
    for (int p = 0; p < nparts; ++p) {
        float mp = part_ml[(recbase + p) * 128 + qi];
        float lp = part_ml[(recbase + p) * 128 + 64 + qi];
        float w = __expf(mp - m);
        L += lp * w;
        const float* po = part_o + (size_t)(recbase + p) * 2048;
        float4 a = *(const float4*)(po + qi * 32 + sub * 4);
        float4 b = *(const float4*)(po + qi * 32 + (sub + 4) * 4);
        O0.x += a.x * w; O0.y += a.y * w; O0.z += a.z * w; O0.w += a.w * w;
        O1.x += b.x * w; O1.y += b.y * w; O1.z += b.z * w; O1.w += b.w * w;
    }
    if (q0 + qi < Ms) {
        float inv = 1.0f / fmaxf(L, 1e-30f);
        size_t orow = ((size_t)s * MC + q0 + qi) * DD + head * DH;
        float4 r0 = make_float4(O0.x * inv, O0.y * inv, O0.z * inv, O0.w * inv);
        float4 r1 = make_float4(O1.x * inv, O1.y * inv, O1.z * inv, O1.w * inv);
        *(float4*)(attno + orow + sub * 4) = r0;
        *(float4*)(attno + orow + (sub + 4) * 4) = r1;
    }
}

// ---------------- x1 = LN1(macro + attno @ Wo.T + bo) ----------------
__global__ void k_ln1(const float* __restrict__ macro, const float* __restrict__ attno,
                      const float* __restrict__ Wo, const float* __restrict__ bo,
                      const float* __restrict__ g, const float* __restrict__ b,
                      float* __restrict__ x1,
                      const int* M0, const int* M1, const int* M2)
{
    int s = blockIdx.y;
    int Ms = getM(s, M0, M1, M2);
    int m = blockIdx.x;
    if (m >= Ms) return;
    __shared__ __align__(16) float os[DD];
    __shared__ float red[4];
    int d = threadIdx.x;  // 128
    size_t row = (size_t)s * MC + m;
    os[d] = attno[row * DD + d];
    __syncthreads();
    const float* w = Wo + ((size_t)s * DD + d) * DD;
    float acc = bo[s * DD + d];
    for (int k = 0; k < DD; k += 4) {
        float4 w4 = *(const float4*)(w + k);
        float4 m4 = *(const float4*)&os[k];
        acc += w4.x * m4.x + w4.y * m4.y + w4.z * m4.z + w4.w * m4.w;
    }
    float xin = macro[row * DD + d] + acc;
    float sum = xin, sq = xin * xin;
    for (int off = 32; off >= 1; off >>= 1) { sum += __shfl_xor(sum, off); sq += __shfl_xor(sq, off); }
    if ((d & 63) == 0) { red[d >> 6] = sum; red[2 + (d >> 6)] = sq; }
    __syncthreads();
    sum = red[0] + red[1]; sq = red[2] + red[3];
    float mean = sum * (1.0f / DD);
    float var = fmaxf(sq * (1.0f / DD) - mean * mean, 0.0f);
    float xh = (xin - mean) * rsqrtf(var + 1e-5f);
    x1[row * DD + d] = xh * g[s * DD + d] + b[s * DD + d];
}

// ---------------- x2 = LN2(x1 + relu(x1@W1.T+b1)@W2.T + b2) ----------------
__global__ void k_ffn(const float* __restrict__ x1,
                      const float* __restrict__ W1, const float* __restrict__ b1,
                      const float* __restrict__ W2, const float* __restrict__ b2,
                      const float* __restrict__ g, const float* __restrict__ bb,
                      float* __restrict__ x2,
                      const int* M0, const int* M1, const int* M2)
{
    int s = blockIdx.y;
    int Ms = getM(s, M0, M1, M2);
    int m = blockIdx.x;
    if (m >= Ms) return;
    __shared__ __align__(16) float xr[DD];
    __shared__ __align__(16) float ts[FFD];
    __shared__ float red[8];
    int tid = threadIdx.x;  // 256
    size_t row = (size_t)s * MC + m;
    if (tid < DD) xr[tid] = x1[row * DD + tid];
    __syncthreads();
    {
        const float* w = W1 + ((size_t)s * FFD + tid) * DD;
        float acc = b1[s * FFD + tid];
        for (int k = 0; k < DD; k += 4) {
            float4 w4 = *(const float4*)(w + k);
            float4 m4 = *(const float4*)&xr[k];
            acc += w4.x * m4.x + w4.y * m4.y + w4.z * m4.z + w4.w * m4.w;
        }
        ts[tid] = fmaxf(acc, 0.0f);
    }
    __syncthreads();
    float xin = 0.0f;
    if (tid < DD) {
        const float* w = W2 + ((size_t)s * DD + tid) * FFD;
        float acc = b2[s * DD + tid];
        for (int k = 0; k < FFD; k += 4) {
            float4 w4 = *(const float4*)(w + k);
            float4 m4 = *(const float4*)&ts[k];
            acc += w4.x * m4.x + w4.y * m4.y + w4.z * m4.z + w4.w * m4.w;
        }
        xin = xr[tid] + acc;
    }
    float sum = xin, sq = xin * xin;
    for (int off = 32; off >= 1; off >>= 1) { sum += __shfl_xor(sum, off); sq += __shfl_xor(sq, off); }
    if ((tid & 63) == 0) { red[tid >> 6] = sum; red[4 + (tid >> 6)] = sq; }
    __syncthreads();
    sum = red[0] + red[1] + red[2] + red[3];
    sq = red[4] + red[5] + red[6] + red[7];
    float mean = sum * (1.0f / DD);
    float var = fmaxf(sq * (1.0f / DD) - mean * mean, 0.0f);
    if (tid < DD) {
        float xh = (xin - mean) * rsqrtf(var + 1e-5f);
        x2[row * DD + tid] = xh * g[s * DD + tid] + bb[s * DD + tid];
    }
}

// ---------------- y_s = x2_s @ Wf[:, 128*(s+1):128*(s+2)].T ----------------
__global__ void k_yproj(const float* __restrict__ x2, const float* __restrict__ Wf,
                        float* __restrict__ y,
                        const int* M0, const int* M1, const int* M2)
{
    int s = blockIdx.y;
    int Ms = getM(s, M0, M1, M2);
    int m = blockIdx.x;
    if (m >= Ms) return;
    __shared__ __align__(16) float xr[DD];
    int d = threadIdx.x;  // 128
    size_t row = (size_t)s * MC + m;
    xr[d] = x2[row * DD + d];
    __syncthreads();
    const float* w = Wf + (size_t)d * (4 * DD) + (s + 1) * DD;
    float acc = 0.0f;
    for (int k = 0; k < DD; k += 4) {
        float4 w4 = *(const float4*)(w + k);
        float4 m4 = *(const float4*)&xr[k];
        acc += w4.x * m4.x + w4.y * m4.y + w4.z * m4.z + w4.w * m4.w;
    }
    y[row * DD + d] = acc;
}

// ---------------- out = h@B0 + y0[inv0] + y1[inv1] + y2[inv2] + bf ----------------
__global__ __launch_bounds__(256) void k_final(const float* __restrict__ h,
                                               const float* __restrict__ B0T,
                                               const float* __restrict__ y,
                                               const int* __restrict__ inv0,
                                               const int* __restrict__ inv1,
                                               const int* __restrict__ inv2,
                                               const float* __restrict__ bf,
                                               float* __restrict__ out, int N)
{
    __shared__ __align__(16) float hs[64][132];
    int tid = threadIdx.x;
    int ntiles = (N + 63) >> 6;
    const float* y0 = y;
    const float* y1 = y + (size_t)MC * DD;
    const float* y2 = y + (size_t)2 * MC * DD;
    for (int t = blockIdx.x; t < ntiles; t += gridDim.x) {
        int pb = t * 64;
        __syncthreads();
        for (int fq = tid; fq < 64 * 32; fq += 256) {
            int p = fq >> 5, q = fq & 31;
            float4 v4 = make_float4(0.f, 0.f, 0.f, 0.f);
            if (pb + p < N) v4 = *(const float4*)(h + ((size_t)(pb + p)) * DD + q * 4);
            *(float4*)&hs[p][q * 4] = v4;
        }
        __syncthreads();
        int pg = tid & 15, dg = tid >> 4;
        int d0 = dg * 8;
        float4 a0[4], a1[4];
#pragma unroll
        for (int i = 0; i < 4; ++i) {
            a0[i] = make_float4(0.f, 0.f, 0.f, 0.f);
            a1[i] = make_float4(0.f, 0.f, 0.f, 0.f);
        }
        for (int k = 0; k < DD; k += 4) {
            float4 h4[4];
#pragma unroll
            for (int i = 0; i < 4; ++i) h4[i] = *(const float4*)&hs[pg + 16 * i][k];
#pragma unroll
            for (int kk = 0; kk < 4; ++kk) {
                float4 ba = *(const float4*)(B0T + (size_t)(k + kk) * DD + d0);
                float4 bb = *(const float4*)(B0T + (size_t)(k + kk) * DD + d0 + 4);
#pragma unroll
                for (int i = 0; i < 4; ++i) {
                    float hv = (kk == 0) ? h4[i].x : (kk == 1) ? h4[i].y : (kk == 2) ? h4[i].z : h4[i].w;
                    a0[i].x += hv * ba.x; a0[i].y += hv * ba.y; a0[i].z += hv * ba.z; a0[i].w += hv * ba.w;
                    a1[i].x += hv * bb.x; a1[i].y += hv * bb.y; a1[i].z += hv * bb.z; a1[i].w += hv * bb.w;
                }
            }
        }
        float4 bf0 = *(const float4*)(bf + d0);
        float4 bf1 = *(const float4*)(bf + d0 + 4);
#pragma unroll
        for (int i = 0; i < 4; ++i) {
            int p = pb + pg + 16 * i;
            if (p >= N) continue;
            int i0 = inv0[p], i1 = inv1[p], i2 = inv2[p];
            float4 g0 = *(const float4*)(y0 + (size_t)i0 * DD + d0);
            float4 g0b = *(const float4*)(y0 + (size_t)i0 * DD + d0 + 4);
            float4 g1 = *(const float4*)(y1 + (size_t)i1 * DD + d0);
            float4 g1b = *(const float4*)(y1 + (size_t)i1 * DD + d0 + 4);
            float4 g2 = *(const float4*)(y2 + (size_t)i2 * DD + d0);
            float4 g2b = *(const float4*)(y2 + (size_t)i2 * DD + d0 + 4);
            float4 r0 = make_float4(a0[i].x + g0.x + g1.x + g2.x + bf0.x,
                                    a0[i].y + g0.y + g1.y + g2.y + bf0.y,
                                    a0[i].z + g0.z + g1.z + g2.z + bf0.z,
                                    a0[i].w + g0.w + g1.w + g2.w + bf0.w);
            float4 r1 = make_float4(a1[i].x + g0b.x + g1b.x + g2b.x + bf1.x,
                                    a1[i].y + g0b.y + g1b.y + g2b.y + bf1.y,
                                    a1[i].z + g0b.z + g1b.z + g2b.z + bf1.z,
                                    a1[i].w + g0b.w + g1b.w + g2b.w + bf1.w);
            *(float4*)(out + (size_t)p * DD + d0) = r0;
            *(float4*)(out + (size_t)p * DD + d0 + 4) = r1;
        }
    }
}

extern "C" void kernel_launch(void* const* d_in, const int* in_sizes, int n_in,
                              void* d_out, int out_size, void* d_ws, size_t ws_size,
                              hipStream_t stream) {
    (void)n_in; (void)out_size; (void)ws_size;
    const float* h   = (const float*)d_in[0];
    const int* inv0  = (const int*)d_in[2];
    const int* inv1  = (const int*)d_in[3];
    const int* inv2  = (const int*)d_in[4];
    const int* M0    = (const int*)d_in[5];
    const int* M1    = (const int*)d_in[6];
    const int* M2    = (const int*)d_in[7];
    const float* Wqkv = (const float*)d_in[8];
    const float* bqkv = (const float*)d_in[9];
    const float* Wo   = (const float*)d_in[10];
    const float* bo   = (const float*)d_in[11];
    const float* ln1s = (const float*)d_in[12];
    const float* ln1b = (const float*)d_in[13];
    const float* W1   = (const float*)d_in[14];
    const float* b1   = (const float*)d_in[15];
    const float* W2   = (const float*)d_in[16];
    const float* b2   = (const float*)d_in[17];
    const float* ln2s = (const float*)d_in[18];
    const float* ln2b = (const float*)d_in[19];
    const float* Wf   = (const float*)d_in[20];
    const float* bf   = (const float*)d_in[21];
    int N = in_sizes[0] / DD;

    float* ws      = (float*)d_ws;
    float* macro   = ws;                                    // NS*MC*DD
    float* counts  = macro + (size_t)NS * MC * DD;          // NS*MC
    float* qkvb    = counts + (size_t)NS * MC;              // NS*MC*3*DD
    float* attno   = qkvb + (size_t)NS * MC * 3 * DD;       // NS*MC*DD
    float* x1      = attno + (size_t)NS * MC * DD;          // NS*MC*DD
    float* x2      = x1 + (size_t)NS * MC * DD;             // NS*MC*DD
    float* yb      = x2 + (size_t)NS * MC * DD;             // NS*MC*DD
    float* B0T     = yb + (size_t)NS * MC * DD;             // DD*DD
    float* part_o  = B0T + (size_t)DD * DD;                 // NS*NHH*64*NSPLIT*2048
    float* part_ml = part_o + (size_t)NS * NHH * 64 * NSPLIT * 2048;  // NS*NHH*64*NSPLIT*128
    int* ip        = (int*)(part_ml + (size_t)NS * NHH * 64 * NSPLIT * 128);
    int* parent10  = ip;                // MC
    int* parent21  = parent10 + MC;     // 512
    int* cnt_i     = parent21 + 512;    // MC
    int* fill      = cnt_i + MC;        // MC
    int* offs      = fill + MC;         // MC
    int* order     = offs + MC;         // N

    float* sum0 = macro;
    float* sum1 = macro + (size_t)1 * MC * DD;
    float* sum2 = macro + (size_t)2 * MC * DD;
    float* cnt0 = counts;
    float* cnt1 = counts + MC;
    float* cnt2 = counts + 2 * MC;

    hipMemsetAsync(macro, 0, ((size_t)NS * MC * DD + NS * MC) * sizeof(float), stream);
    hipMemsetAsync(cnt_i, 0, (size_t)2 * MC * sizeof(int), stream);

    int nb = (N + 255) / 256;
    k_parent<<<nb, 256, 0, stream>>>(inv0, inv1, inv2, parent10, parent21, cnt_i, N);
    k_scan<<<1, 1024, 0, stream>>>(cnt_i, offs);
    k_place<<<nb, 256, 0, stream>>>(inv0, offs, fill, order, N);
    k_pool<<<MC, 256, 0, stream>>>(h, order, offs, cnt_i, sum0, cnt0, M0);
    k_rollup<<<(MC * DD) / 256, 256, 0, stream>>>(sum0, cnt0, parent10, sum1, cnt1, M0, MC);
    k_rollup<<<(512 * DD) / 256, 256, 0, stream>>>(sum1, cnt1, parent21, sum2, cnt2, M1, 512);
    k_finalize<<<(NS * MC * DD) / 256, 256, 0, stream>>>(macro, counts, M0, M1, M2);
    k_b0t<<<64, 256, 0, stream>>>(Wf, B0T);
    k_qkv<<<dim3(MC / 8, NS), 256, 0, stream>>>(macro, Wqkv, bqkv, qkvb, M0, M1, M2);
    k_attn_part<<<dim3(MC / 64, NHH, NS * NSPLIT), 256, 0, stream>>>(qkvb, part_o, part_ml, M0, M1, M2);
    k_attn_comb<<<dim3(MC / 64, NHH, NS), 256, 0, stream>>>(part_o, part_ml, attno, M0, M1, M2);
    k_ln1<<<dim3(MC, NS), 128, 0, stream>>>(macro, attno, Wo, bo, ln1s, ln1b, x1, M0, M1, M2);
    k_ffn<<<dim3(MC, NS), 256, 0, stream>>>(x1, W1, b1, W2, b2, ln2s, ln2b, x2, M0, M1, M2);
    k_yproj<<<dim3(MC, NS), 128, 0, stream>>>(x2, Wf, yb, M0, M1, M2);
    k_final<<<2048, 256, 0, stream>>>(h, B0T, yb, inv0, inv1, inv2, bf, (float*)d_out, N);
}

// Round 6
// 1056.783 us; speedup vs baseline: 2.7401x; 1.0827x over previous
//
#include <hip/hip_runtime.h>
#include <hip/hip_bf16.h>

#define MC 4096
#define DD 128
#define NHH 4
#define DH 32
#define FFD 256
#define NS 3
#define NSPLIT 4
#define PLEN 1024

typedef __attribute__((ext_vector_type(8))) short short8_t;
typedef __attribute__((ext_vector_type(4))) float f32x4;

__device__ __forceinline__ int getM(int s, const int* M0, const int* M1, const int* M2) {
    return (s == 0) ? *M0 : (s == 1) ? *M1 : *M2;
}

__device__ __forceinline__ unsigned short f2bf(float f) {
    unsigned int u = __float_as_uint(f);
    u += 0x7FFFu + ((u >> 16) & 1u);   // RNE
    return (unsigned short)(u >> 16);
}

// ---------------- parent maps + scale-0 histogram in one pass ----------------
__global__ void k_parent(const int* __restrict__ inv0, const int* __restrict__ inv1,
                         const int* __restrict__ inv2,
                         int* __restrict__ parent10, int* __restrict__ parent21,
                         int* __restrict__ cnt, int N)
{
    int n = blockIdx.x * blockDim.x + threadIdx.x;
    if (n >= N) return;
    int i0 = inv0[n];
    parent10[i0] = inv1[n];   // duplicate writes all agree (grids nest)
    parent21[inv1[n]] = inv2[n];
    atomicAdd(&cnt[i0], 1);
}

// ---------------- exclusive scan over MC=4096 bins, single block 1024 thr ----------------
__global__ void k_scan(const int* __restrict__ cnt, int* __restrict__ offs)
{
    __shared__ int arr[1024];
    int tid = threadIdx.x;
    int base = tid * 4;
    int c0 = cnt[base], c1 = cnt[base + 1], c2 = cnt[base + 2], c3 = cnt[base + 3];
    int tot = c0 + c1 + c2 + c3;
    arr[tid] = tot;
    __syncthreads();
    for (int off = 1; off < 1024; off <<= 1) {
        int v = (tid >= off) ? arr[tid - off] : 0;
        __syncthreads();
        arr[tid] += v;
        __syncthreads();
    }
    int excl = arr[tid] - tot;
    offs[base] = excl;
    offs[base + 1] = excl + c0;
    offs[base + 2] = excl + c0 + c1;
    offs[base + 3] = excl + c0 + c1 + c2;
}

// ---------------- placement: order[] groups particles by voxel ----------------
__global__ void k_place(const int* __restrict__ inv0, const int* __restrict__ offs,
                        int* __restrict__ fill, int* __restrict__ order, int N)
{
    int n = blockIdx.x * blockDim.x + threadIdx.x;
    if (n >= N) return;
    int i0 = inv0[n];
    int pos = offs[i0] + atomicAdd(&fill[i0], 1);
    order[pos] = n;
}

// ---------------- pooled sums, no fp atomics: one block per voxel ----------------
__global__ __launch_bounds__(256) void k_pool(const float* __restrict__ h,
                                              const int* __restrict__ order,
                                              const int* __restrict__ offs,
                                              const int* __restrict__ cnt,
                                              float* __restrict__ sum0, float* __restrict__ cnt0,
                                              const int* __restrict__ M0)
{
    int v = blockIdx.x;
    if (v >= *M0) return;
    int beg = offs[v], len = cnt[v];
    int tid = threadIdx.x;
    int d = tid & 127, half = tid >> 7;
    float acc = 0.f;
    for (int j = half; j < len; j += 2) {
        int row = order[beg + j];
        acc += h[(size_t)row * DD + d];
    }
    __shared__ float red[DD];
    if (half == 1) red[d] = acc;
    __syncthreads();
    if (half == 0) {
        acc += red[d];
        sum0[(size_t)v * DD + d] = acc;
        if (d == 0) cnt0[v] = (float)len;
    }
}

// ---------------- roll coarse sums up the hierarchy ----------------
__global__ void k_rollup(const float* __restrict__ sumSrc, const float* __restrict__ cntSrc,
                         const int* __restrict__ parent,
                         float* __restrict__ sumDst, float* __restrict__ cntDst,
                         const int* __restrict__ Msrc, int cap)
{
    int idx = blockIdx.x * blockDim.x + threadIdx.x;   // < cap*DD
    int v = idx >> 7, d = idx & 127;
    int Ms = *Msrc;
    if (Ms > cap) Ms = cap;
    if (v >= Ms) return;
    int p = parent[v];
    atomicAdd(&sumDst[(size_t)p * DD + d], sumSrc[idx]);
    if (d == 0) atomicAdd(&cntDst[p], cntSrc[v]);
}

// ---------------- divide by clamped counts ----------------
__global__ void k_finalize(float* __restrict__ macro, const float* __restrict__ counts,
                           const int* M0, const int* M1, const int* M2)
{
    int idx = blockIdx.x * blockDim.x + threadIdx.x;  // < NS*MC*DD
    int s = idx / (MC * DD);
    int r = (idx >> 7) & (MC - 1);
    if (r >= getM(s, M0, M1, M2)) return;
    float c = counts[s * MC + r];
    macro[idx] /= fmaxf(c, 1.0f);
}

// ---------------- b0frag: MFMA B-operand fragments of Wf[:, :128] in bf16 ----------------
// b0f[((nt*4+kt)*64 + l)*8 + j] = bf16( Wf[nt*16 + (l&15)][kt*32 + (l>>4)*8 + j] )
__global__ void k_b0frag(const float* __restrict__ Wf, unsigned short* __restrict__ b0f)
{
    int idx = blockIdx.x * 256 + threadIdx.x;  // 16384
    int j = idx & 7, l = (idx >> 3) & 63, kt = (idx >> 9) & 3, nt = idx >> 11;
    int d = nt * 16 + (l & 15);
    int k = kt * 32 + (l >> 4) * 8 + j;
    b0f[idx] = f2bf(Wf[(size_t)d * (4 * DD) + k]);
}

// ---------------- qkv = macro @ Wqkv[s].T + bqkv[s], 8 rows/block ----------------
__global__ void k_qkv(const float* __restrict__ macro, const float* __restrict__ Wqkv,
                      const float* __restrict__ bqkv, float* __restrict__ qkv,
                      const int* M0, const int* M1, const int* M2)
{
    int s = blockIdx.y;
    int Ms = getM(s, M0, M1, M2);
    int row0 = blockIdx.x * 8;
    if (row0 >= Ms) return;
    __shared__ __align__(16) float mac[8][DD];
    int tid = threadIdx.x;
    for (int e = tid; e < 8 * DD; e += 256) {
        int r = e >> 7, d = e & 127;
        int row = row0 + r;
        mac[r][d] = (row < Ms) ? macro[(size_t)s * MC * DD + (size_t)row * DD + d] : 0.0f;
    }
    __syncthreads();
    for (int j = tid; j < 3 * DD; j += 256) {
        const float* w = Wqkv + ((size_t)s * 3 * DD + j) * DD;
        float b = bqkv[s * 3 * DD + j];
        float acc[8];
#pragma unroll
        for (int r = 0; r < 8; ++r) acc[r] = b;
        for (int k = 0; k < DD; k += 4) {
            float4 w4 = *(const float4*)(w + k);
#pragma unroll
            for (int r = 0; r < 8; ++r) {
                float4 m4 = *(const float4*)&mac[r][k];
                acc[r] += w4.x * m4.x + w4.y * m4.y + w4.z * m4.z + w4.w * m4.w;
            }
        }
        for (int r = 0; r < 8; ++r) {
            int row = row0 + r;
            if (row < Ms) qkv[((size_t)s * MC + row) * (3 * DD) + j] = acc[r];
        }
    }
}

// ---------------- flash attention partials: LDS-staged K/V, register p/m/l/o ----------------
__global__ __launch_bounds__(256) void k_attn_part(const float* __restrict__ qkv,
                                                   float* __restrict__ part_o,
                                                   float* __restrict__ part_ml,
                                                   const int* M0, const int* M1, const int* M2)
{
    int z = blockIdx.z;
    int s = z / NSPLIT, part = z % NSPLIT;
    int head = blockIdx.y;
    int Ms = getM(s, M0, M1, M2);
    int q0 = blockIdx.x * 64;
    if (q0 >= Ms) return;
    int kstart = part * PLEN;
    if (kstart >= Ms) return;
    int kend = kstart + PLEN; if (kend > Ms) kend = Ms;

    __shared__ __align__(16) float ks[64][36];
    __shared__ __align__(16) float vs[64][36];

    int tid = threadIdx.x;
    int qi = tid >> 2, sub = tid & 3;
    int qrow = q0 + qi;

    const float* base = qkv + (size_t)s * MC * 3 * DD;
    const float* Qb = base + head * DH;
    const float* Kb = base + DD + head * DH;
    const float* Vb = base + 2 * DD + head * DH;

    float4 q4[8];
#pragma unroll
    for (int r = 0; r < 8; ++r) q4[r] = make_float4(0.f, 0.f, 0.f, 0.f);
    if (qrow < Ms) {
#pragma unroll
        for (int r = 0; r < 8; ++r) q4[r] = *(const float4*)(Qb + (size_t)qrow * 3 * DD + r * 4);
    }

    float4 o4[8];
#pragma unroll
    for (int r = 0; r < 8; ++r) o4[r] = make_float4(0.f, 0.f, 0.f, 0.f);
    float m = -1e30f, l = 0.f;
    const float scale = 0.1767766952966369f;  // 1/sqrt(32)

    for (int kb = kstart; kb < kend; kb += 64) {
        __syncthreads();   // previous chunk's readers done
        for (int e = tid; e < 64 * 8; e += 256) {
            int r = e >> 3, qq = e & 7;
            int key = kb + r;
            float4 kv4 = make_float4(0.f, 0.f, 0.f, 0.f);
            float4 vv4 = make_float4(0.f, 0.f, 0.f, 0.f);
            if (key < kend) {
                kv4 = *(const float4*)(Kb + (size_t)key * 3 * DD + qq * 4);
                vv4 = *(const float4*)(Vb + (size_t)key * 3 * DD + qq * 4);
            }
            *(float4*)&ks[r][qq * 4] = kv4;
            *(float4*)&vs[r][qq * 4] = vv4;
        }
        __syncthreads();

        float p[16];
#pragma unroll 4
        for (int j = 0; j < 16; ++j) {
            int kk = j * 4 + sub;
            float acc = 0.f;
#pragma unroll
            for (int r = 0; r < 8; ++r) {
                float4 kv = *(const float4*)&ks[kk][r * 4];
                acc += q4[r].x * kv.x + q4[r].y * kv.y + q4[r].z * kv.z + q4[r].w * kv.w;
            }
            p[j] = (kb + kk < kend) ? acc * scale : -1e30f;
        }
        float lmax = p[0];
#pragma unroll
        for (int j = 1; j < 16; ++j) lmax = fmaxf(lmax, p[j]);
        lmax = fmaxf(lmax, __shfl_xor(lmax, 1));
        lmax = fmaxf(lmax, __shfl_xor(lmax, 2));
        float mnew = fmaxf(m, lmax);
        float alpha = __expf(m - mnew);
        m = mnew;
        l *= alpha;
#pragma unroll
        for (int r = 0; r < 8; ++r) {
            o4[r].x *= alpha; o4[r].y *= alpha; o4[r].z *= alpha; o4[r].w *= alpha;
        }
        float lsum = 0.f;
#pragma unroll
        for (int j = 0; j < 16; ++j) {
            float e = __expf(p[j] - mnew);
            p[j] = e;
            lsum += e;
        }
#pragma unroll 4
        for (int j = 0; j < 16; ++j) {
            int kk = j * 4 + sub;
            float pv = p[j];
#pragma unroll
            for (int r = 0; r < 8; ++r) {
                float4 vv = *(const float4*)&vs[kk][r * 4];
                o4[r].x += pv * vv.x; o4[r].y += pv * vv.y;
                o4[r].z += pv * vv.z; o4[r].w += pv * vv.w;
            }
        }
        lsum += __shfl_xor(lsum, 1);
        lsum += __shfl_xor(lsum, 2);
        l += lsum;
    }

#pragma unroll
    for (int r = 0; r < 8; ++r) {
        o4[r].x += __shfl_xor(o4[r].x, 1); o4[r].y += __shfl_xor(o4[r].y, 1);
        o4[r].z += __shfl_xor(o4[r].z, 1); o4[r].w += __shfl_xor(o4[r].w, 1);
        o4[r].x += __shfl_xor(o4[r].x, 2); o4[r].y += __shfl_xor(o4[r].y, 2);
        o4[r].z += __shfl_xor(o4[r].z, 2); o4[r].w += __shfl_xor(o4[r].w, 2);
    }

    int rec = ((s * NHH + head) * 64 + blockIdx.x) * NSPLIT + part;
    float* po = part_o + (size_t)rec * 2048;
    *(float4*)(po + qi * 32 + sub * 8)     = o4[2 * sub];
    *(float4*)(po + qi * 32 + sub * 8 + 4) = o4[2 * sub + 1];
    if (sub == 0) {
        part_ml[rec * 128 + qi] = m;
        part_ml[rec * 128 + 64 + qi] = l;
    }
}

// ---------------- merge split-K partials ----------------
__global__ void k_attn_comb(const float* __restrict__ part_o, const float* __restrict__ part_ml,
                            float* __restrict__ attno,
                            const int* M0, const int* M1, const int* M2)
{
    int s = blockIdx.z, head = blockIdx.y;
    int Ms = getM(s, M0, M1, M2);
    int q0 = blockIdx.x * 64;
    if (q0 >= Ms) return;
    int tid = threadIdx.x;
    int qi = tid >> 2, sub = tid & 3;
    int nparts = (Ms + PLEN - 1) / PLEN;
    if (nparts > NSPLIT) nparts = NSPLIT;
    int recbase = ((s * NHH + head) * 64 + blockIdx.x) * NSPLIT;

    float m = -1e30f;
    for (int p = 0; p < nparts; ++p)
        m = fmaxf(m, part_ml[(recbase + p) * 128 + qi]);
    float L = 0.f;
    float4 O0 = make_float4(0.f, 0.f, 0.f, 0.f);
    float4 O1 = make_float4(0.f, 0.f, 0.f, 0.f);
    for (int p = 0; p < nparts; ++p) {
        float mp = part_ml[(recbase + p) * 128 + qi];
        float lp = part_ml[(recbase + p) * 128 + 64 + qi];
        float w = __expf(mp - m);
        L += lp * w;
        const float* po = part_o + (size_t)(recbase + p) * 2048;
        float4 a = *(const float4*)(po + qi * 32 + sub * 4);
        float4 b = *(const float4*)(po + qi * 32 + (sub + 4) * 4);
        O0.x += a.x * w; O0.y += a.y * w; O0.z += a.z * w; O0.w += a.w * w;
        O1.x += b.x * w; O1.y += b.y * w; O1.z += b.z * w; O1.w += b.w * w;
    }
    if (q0 + qi < Ms) {
        float inv = 1.0f / fmaxf(L, 1e-30f);
        size_t orow = ((size_t)s * MC + q0 + qi) * DD + head * DH;
        float4 r0 = make_float4(O0.x * inv, O0.y * inv, O0.z * inv, O0.w * inv);
        float4 r1 = make_float4(O1.x * inv, O1.y * inv, O1.z * inv, O1.w * inv);
        *(float4*)(attno + orow + sub * 4) = r0;
        *(float4*)(attno + orow + (sub + 4) * 4) = r1;
    }
}

// ---------------- x1 = LN1(macro + attno @ Wo.T + bo) ----------------
__global__ void k_ln1(const float* __restrict__ macro, const float* __restrict__ attno,
                      const float* __restrict__ Wo, const float* __restrict__ bo,
                      const float* __restrict__ g, const float* __restrict__ b,
                      float* __restrict__ x1,
                      const int* M0, const int* M1, const int* M2)
{
    int s = blockIdx.y;
    int Ms = getM(s, M0, M1, M2);
    int m = blockIdx.x;
    if (m >= Ms) return;
    __shared__ __align__(16) float os[DD];
    __shared__ float red[4];
    int d = threadIdx.x;  // 128
    size_t row = (size_t)s * MC + m;
    os[d] = attno[row * DD + d];
    __syncthreads();
    const float* w = Wo + ((size_t)s * DD + d) * DD;
    float acc = bo[s * DD + d];
    for (int k = 0; k < DD; k += 4) {
        float4 w4 = *(const float4*)(w + k);
        float4 m4 = *(const float4*)&os[k];
        acc += w4.x * m4.x + w4.y * m4.y + w4.z * m4.z + w4.w * m4.w;
    }
    float xin = macro[row * DD + d] + acc;
    float sum = xin, sq = xin * xin;
    for (int off = 32; off >= 1; off >>= 1) { sum += __shfl_xor(sum, off); sq += __shfl_xor(sq, off); }
    if ((d & 63) == 0) { red[d >> 6] = sum; red[2 + (d >> 6)] = sq; }
    __syncthreads();
    sum = red[0] + red[1]; sq = red[2] + red[3];
    float mean = sum * (1.0f / DD);
    float var = fmaxf(sq * (1.0f / DD) - mean * mean, 0.0f);
    float xh = (xin - mean) * rsqrtf(var + 1e-5f);
    x1[row * DD + d] = xh * g[s * DD + d] + b[s * DD + d];
}

// ---------------- x2 = LN2(x1 + relu(x1@W1.T+b1)@W2.T + b2) ----------------
__global__ void k_ffn(const float* __restrict__ x1,
                      const float* __restrict__ W1, const float* __restrict__ b1,
                      const float* __restrict__ W2, const float* __restrict__ b2,
                      const float* __restrict__ g, const float* __restrict__ bb,
                      float* __restrict__ x2,
                      const int* M0, const int* M1, const int* M2)
{
    int s = blockIdx.y;
    int Ms = getM(s, M0, M1, M2);
    int m = blockIdx.x;
    if (m >= Ms) return;
    __shared__ __align__(16) float xr[DD];
    __shared__ __align__(16) float ts[FFD];
    __shared__ float red[8];
    int tid = threadIdx.x;  // 256
    size_t row = (size_t)s * MC + m;
    if (tid < DD) xr[tid] = x1[row * DD + tid];
    __syncthreads();
    {
        const float* w = W1 + ((size_t)s * FFD + tid) * DD;
        float acc = b1[s * FFD + tid];
        for (int k = 0; k < DD; k += 4) {
            float4 w4 = *(const float4*)(w + k);
            float4 m4 = *(const float4*)&xr[k];
            acc += w4.x * m4.x + w4.y * m4.y + w4.z * m4.z + w4.w * m4.w;
        }
        ts[tid] = fmaxf(acc, 0.0f);
    }
    __syncthreads();
    float xin = 0.0f;
    if (tid < DD) {
        const float* w = W2 + ((size_t)s * DD + tid) * FFD;
        float acc = b2[s * DD + tid];
        for (int k = 0; k < FFD; k += 4) {
            float4 w4 = *(const float4*)(w + k);
            float4 m4 = *(const float4*)&ts[k];
            acc += w4.x * m4.x + w4.y * m4.y + w4.z * m4.z + w4.w * m4.w;
        }
        xin = xr[tid] + acc;
    }
    float sum = xin, sq = xin * xin;
    for (int off = 32; off >= 1; off >>= 1) { sum += __shfl_xor(sum, off); sq += __shfl_xor(sq, off); }
    if ((tid & 63) == 0) { red[tid >> 6] = sum; red[4 + (tid >> 6)] = sq; }
    __syncthreads();
    sum = red[0] + red[1] + red[2] + red[3];
    sq = red[4] + red[5] + red[6] + red[7];
    float mean = sum * (1.0f / DD);
    float var = fmaxf(sq * (1.0f / DD) - mean * mean, 0.0f);
    if (tid < DD) {
        float xh = (xin - mean) * rsqrtf(var + 1e-5f);
        x2[row * DD + tid] = xh * g[s * DD + tid] + bb[s * DD + tid];
    }
}

// ---------------- y_s = x2_s @ Wf[:, 128*(s+1):128*(s+2)].T ----------------
__global__ void k_yproj(const float* __restrict__ x2, const float* __restrict__ Wf,
                        float* __restrict__ y,
                        const int* M0, const int* M1, const int* M2)
{
    int s = blockIdx.y;
    int Ms = getM(s, M0, M1, M2);
    int m = blockIdx.x;
    if (m >= Ms) return;
    __shared__ __align__(16) float xr[DD];
    int d = threadIdx.x;  // 128
    size_t row = (size_t)s * MC + m;
    xr[d] = x2[row * DD + d];
    __syncthreads();
    const float* w = Wf + (size_t)d * (4 * DD) + (s + 1) * DD;
    float acc = 0.0f;
    for (int k = 0; k < DD; k += 4) {
        float4 w4 = *(const float4*)(w + k);
        float4 m4 = *(const float4*)&xr[k];
        acc += w4.x * m4.x + w4.y * m4.y + w4.z * m4.z + w4.w * m4.w;
    }
    y[row * DD + d] = acc;
}

// ---------------- out = h@B0 (bf16 MFMA) + y0[inv0]+y1[inv1]+y2[inv2] + bf ----------------
// 64-particle tiles; wave w owns 16 particles. A-frag: 8 consecutive bf16 along K
// at row lane&15 (k-block lane>>4). B-frags precomputed in b0f. C/D: row=(l>>4)*4+reg
// (particle), col=l&15 (dim) [m89-verified layout].
__global__ __launch_bounds__(256) void k_final(const float* __restrict__ h,
                                               const unsigned short* __restrict__ b0f,
                                               const float* __restrict__ y,
                                               const int* __restrict__ inv0,
                                               const int* __restrict__ inv1,
                                               const int* __restrict__ inv2,
                                               const float* __restrict__ bf,
                                               float* __restrict__ out, int N)
{
    __shared__ __align__(16) unsigned short hs[64][136];  // 272B row: 4-bank shift, 16B aligned
    __shared__ int ivs[3][64];
    int tid = threadIdx.x;
    int wave = tid >> 6, lane = tid & 63;
    int ntiles = (N + 63) >> 6;
    const float* y0 = y;
    const float* y1 = y + (size_t)MC * DD;
    const float* y2 = y + (size_t)2 * MC * DD;

    for (int t = blockIdx.x; t < ntiles; t += gridDim.x) {
        int pb = t * 64;
        __syncthreads();  // previous tile's readers done
        if (tid < 64) {
            int p = pb + tid;
            ivs[0][tid] = (p < N) ? inv0[p] : 0;
        } else if (tid < 128) {
            int p = pb + tid - 64;
            ivs[1][tid - 64] = (p < N) ? inv1[p] : 0;
        } else if (tid < 192) {
            int p = pb + tid - 128;
            ivs[2][tid - 128] = (p < N) ? inv2[p] : 0;
        }
        for (int e = tid; e < 64 * 32; e += 256) {   // 64 rows x 32 float4-units
            int row = e >> 5, u = e & 31;
            int p = pb + row;
            float4 v4 = make_float4(0.f, 0.f, 0.f, 0.f);
            if (p < N) v4 = *(const float4*)(h + (size_t)p * DD + u * 4);
            ushort4 b;
            b.x = f2bf(v4.x); b.y = f2bf(v4.y); b.z = f2bf(v4.z); b.w = f2bf(v4.w);
            *(ushort4*)&hs[row][u * 4] = b;
        }
        __syncthreads();

        // A fragments: 4 K-blocks, row = wave*16 + (lane&15), k = kt*32 + (lane>>4)*8
        short8_t afr[4];
#pragma unroll
        for (int kt = 0; kt < 4; ++kt)
            afr[kt] = *(const short8_t*)&hs[wave * 16 + (lane & 15)][kt * 32 + (lane >> 4) * 8];

#pragma unroll
        for (int nt = 0; nt < 8; ++nt) {
            f32x4 acc = {0.f, 0.f, 0.f, 0.f};
#pragma unroll
            for (int kt = 0; kt < 4; ++kt) {
                short8_t bfr = *(const short8_t*)(b0f + (size_t)((nt * 4 + kt) * 64 + lane) * 8);
                acc = __builtin_amdgcn_mfma_f32_16x16x32_bf16(afr[kt], bfr, acc, 0, 0, 0);
            }
            int d = nt * 16 + (lane & 15);
            float bias = bf[d];
#pragma unroll
            for (int reg = 0; reg < 4; ++reg) {
                int pl = wave * 16 + (lane >> 4) * 4 + reg;
                int p = pb + pl;
                if (p < N) {
                    int i0 = ivs[0][pl], i1 = ivs[1][pl], i2 = ivs[2][pl];
                    out[(size_t)p * DD + d] = acc[reg]
                        + y0[(size_t)i0 * DD + d] + y1[(size_t)i1 * DD + d]
                        + y2[(size_t)i2 * DD + d] + bias;
                }
            }
        }
    }
}

extern "C" void kernel_launch(void* const* d_in, const int* in_sizes, int n_in,
                              void* d_out, int out_size, void* d_ws, size_t ws_size,
                              hipStream_t stream) {
    (void)n_in; (void)out_size; (void)ws_size;
    const float* h   = (const float*)d_in[0];
    const int* inv0  = (const int*)d_in[2];
    const int* inv1  = (const int*)d_in[3];
    const int* inv2  = (const int*)d_in[4];
    const int* M0    = (const int*)d_in[5];
    const int* M1    = (const int*)d_in[6];
    const int* M2    = (const int*)d_in[7];
    const float* Wqkv = (const float*)d_in[8];
    const float* bqkv = (const float*)d_in[9];
    const float* Wo   = (const float*)d_in[10];
    const float* bo   = (const float*)d_in[11];
    const float* ln1s = (const float*)d_in[12];
    const float* ln1b = (const float*)d_in[13];
    const float* W1   = (const float*)d_in[14];
    const float* b1   = (const float*)d_in[15];
    const float* W2   = (const float*)d_in[16];
    const float* b2   = (const float*)d_in[17];
    const float* ln2s = (const float*)d_in[18];
    const float* ln2b = (const float*)d_in[19];
    const float* Wf   = (const float*)d_in[20];
    const float* bf   = (const float*)d_in[21];
    int N = in_sizes[0] / DD;

    float* ws      = (float*)d_ws;
    float* macro   = ws;                                    // NS*MC*DD
    float* counts  = macro + (size_t)NS * MC * DD;          // NS*MC
    float* qkvb    = counts + (size_t)NS * MC;              // NS*MC*3*DD
    float* attno   = qkvb + (size_t)NS * MC * 3 * DD;       // NS*MC*DD
    float* x1      = attno + (size_t)NS * MC * DD;          // NS*MC*DD
    float* x2      = x1 + (size_t)NS * MC * DD;             // NS*MC*DD
    float* yb      = x2 + (size_t)NS * MC * DD;             // NS*MC*DD
    float* b0f_f   = yb + (size_t)NS * MC * DD;             // DD*DD floats of space (b0f uses half)
    unsigned short* b0f = (unsigned short*)b0f_f;
    float* part_o  = b0f_f + (size_t)DD * DD;               // NS*NHH*64*NSPLIT*2048
    float* part_ml = part_o + (size_t)NS * NHH * 64 * NSPLIT * 2048;  // NS*NHH*64*NSPLIT*128
    int* ip        = (int*)(part_ml + (size_t)NS * NHH * 64 * NSPLIT * 128);
    int* parent10  = ip;                // MC
    int* parent21  = parent10 + MC;     // 512
    int* cnt_i     = parent21 + 512;    // MC
    int* fill      = cnt_i + MC;        // MC
    int* offs      = fill + MC;         // MC
    int* order     = offs + MC;         // N

    float* sum0 = macro;
    float* sum1 = macro + (size_t)1 * MC * DD;
    float* sum2 = macro + (size_t)2 * MC * DD;
    float* cnt0 = counts;
    float* cnt1 = counts + MC;
    float* cnt2 = counts + 2 * MC;

    hipMemsetAsync(macro, 0, ((size_t)NS * MC * DD + NS * MC) * sizeof(float), stream);
    hipMemsetAsync(cnt_i, 0, (size_t)2 * MC * sizeof(int), stream);

    int nb = (N + 255) / 256;
    k_parent<<<nb, 256, 0, stream>>>(inv0, inv1, inv2, parent10, parent21, cnt_i, N);
    k_scan<<<1, 1024, 0, stream>>>(cnt_i, offs);
    k_place<<<nb, 256, 0, stream>>>(inv0, offs, fill, order, N);
    k_pool<<<MC, 256, 0, stream>>>(h, order, offs, cnt_i, sum0, cnt0, M0);
    k_rollup<<<(MC * DD) / 256, 256, 0, stream>>>(sum0, cnt0, parent10, sum1, cnt1, M0, MC);
    k_rollup<<<(512 * DD) / 256, 256, 0, stream>>>(sum1, cnt1, parent21, sum2, cnt2, M1, 512);
    k_finalize<<<(NS * MC * DD) / 256, 256, 0, stream>>>(macro, counts, M0, M1, M2);
    k_b0frag<<<64, 256, 0, stream>>>(Wf, b0f);
    k_qkv<<<dim3(MC / 8, NS), 256, 0, stream>>>(macro, Wqkv, bqkv, qkvb, M0, M1, M2);
    k_attn_part<<<dim3(MC / 64, NHH, NS * NSPLIT), 256, 0, stream>>>(qkvb, part_o, part_ml, M0, M1, M2);
    k_attn_comb<<<dim3(MC / 64, NHH, NS), 256, 0, stream>>>(part_o, part_ml, attno, M0, M1, M2);
    k_ln1<<<dim3(MC, NS), 128, 0, stream>>>(macro, attno, Wo, bo, ln1s, ln1b, x1, M0, M1, M2);
    k_ffn<<<dim3(MC, NS), 256, 0, stream>>>(x1, W1, b1, W2, b2, ln2s, ln2b, x2, M0, M1, M2);
    k_yproj<<<dim3(MC, NS), 128, 0, stream>>>(x2, Wf, yb, M0, M1, M2);
    k_final<<<2048, 256, 0, stream>>>(h, b0f, yb, inv0, inv1, inv2, bf, (float*)d_out, N);
}